// Round 1
// baseline (295.172 us; speedup 1.0000x reference)
//
#include <hip/hip_runtime.h>
#include <hip/hip_fp16.h>

#define N_NODES 50000
#define N_EDGES 800000
#define N_GRAPHS 128
#define IN_CH 31
#define HID 64

typedef __attribute__((ext_vector_type(8))) short short8;
typedef __attribute__((ext_vector_type(8))) unsigned short ushort8;
typedef __attribute__((ext_vector_type(4))) float floatx4;
typedef __attribute__((ext_vector_type(8))) _Float16 half8;

__device__ inline unsigned short f2h(float f) {          // fp32 -> fp16 bits
    __half h = __float2half_rn(f);
    return __half_as_ushort(h);
}
__device__ inline unsigned packh2(float a, float b) {    // half2 {a,b} bits
    __half2 h = __floats2half2_rn(a, b);
    return *(unsigned*)&h;
}
__device__ inline void pack4h(short* p, float4 v) {      // p 8B-aligned
    unsigned lo = packh2(v.x, v.y);
    unsigned hi = packh2(v.z, v.w);
    *(uint2*)p = make_uint2(lo, hi);
}
__device__ inline unsigned packEP(float E, float P) {    // half2 {E,P}
    return packh2(E, P);
}
__device__ inline float2 unpackEP(unsigned u) {
    __half2 h = *(__half2*)&u;
    return __half22float2(h);
}

// ---------------- prep: x -> xh (fp16) + EP0 (layer-1 softmax terms) --------
__global__ void prep_kernel(const float* __restrict__ x, const float* __restrict__ tptr,
                            unsigned short* __restrict__ xh, unsigned* __restrict__ EP0,
                            int nN) {
    int i = blockIdx.x * 256 + threadIdx.x;
    if (i >= nN * 32) return;
    int node = i >> 5, c = i & 31;
    if (c < IN_CH) {
        float xv = x[node * IN_CH + c];
        xh[node * IN_CH + c] = f2h(xv);
        float tval = tptr[0];
        float E = __expf(tval * xv);
        EP0[i] = packEP(E, xv * E);
    } else {
        EP0[i] = 0;
    }
}

// ---------------- CSR build: single-pass capacity-padded bucket sort --------
// Buckets of 128 nodes (dst>>7) with fixed capacity CAP: no global hist/scan
// (dst uniform-random: bucket mean 2046, CAP=2560 = +11 sigma).
// ebuf packs src (bits 0..15, N<65536) | local-dst (bits 16..22).

#define BKT_SHIFT 7
#define BKT_MAX 512
#define CHUNK 8192
#define CAP 2560

__global__ void bucket_scatter_kernel(const int* __restrict__ src,
                                      const int* __restrict__ dst,
                                      int* __restrict__ bucket_cnt,
                                      unsigned* __restrict__ ebuf, int e, int nb) {
    __shared__ int bins[BKT_MAX];
    __shared__ int base[BKT_MAX];
    __shared__ int lcur[BKT_MAX];
    int tid = threadIdx.x;
    int i0 = blockIdx.x * CHUNK;
    int i1 = i0 + CHUNK; if (i1 > e) i1 = e;
    for (int k = tid; k < nb; k += 256) { bins[k] = 0; lcur[k] = 0; }
    __syncthreads();
    for (int j = i0 + tid; j < i1; j += 256)
        atomicAdd(&bins[dst[j] >> BKT_SHIFT], 1);
    __syncthreads();
    for (int k = tid; k < nb; k += 256)
        if (bins[k]) base[k] = atomicAdd(&bucket_cnt[k], bins[k]);
    __syncthreads();
    for (int j = i0 + tid; j < i1; j += 256) {
        int ss = src[j], dd = dst[j];
        int b = dd >> BKT_SHIFT;
        int p = atomicAdd(&lcur[b], 1);
        ebuf[(size_t)b * CAP + base[b] + p] = (unsigned)ss | ((unsigned)(dd & 127) << 16);
    }
}

__global__ void bucket_csr_kernel(const unsigned* __restrict__ ebuf,
                                  const int* __restrict__ bucket_cnt,
                                  int* __restrict__ row_ptr, int* __restrict__ deg,
                                  int* __restrict__ csr_src, int nN) {
    __shared__ int nh[128];
    __shared__ int s[128];
    __shared__ int ncur[128];
    int tid = threadIdx.x;
    int b = blockIdx.x;
    int cnt = bucket_cnt[b];
    size_t boff = (size_t)b * CAP;
    int node0 = b << BKT_SHIFT;
    if (tid < 128) nh[tid] = 0;
    __syncthreads();
    for (int j = tid; j < cnt; j += 256)
        atomicAdd(&nh[ebuf[boff + j] >> 16], 1);
    __syncthreads();
    int v = (tid < 128) ? nh[tid] : 0;
    if (tid < 128) s[tid] = v;
    __syncthreads();
    for (int off = 1; off < 128; off <<= 1) {
        int u = (tid < 128 && tid >= off) ? s[tid - off] : 0;
        __syncthreads();
        if (tid < 128) s[tid] += u;
        __syncthreads();
    }
    if (tid < 128 && node0 + tid < nN) {
        int excl = (int)boff + s[tid] - v;
        row_ptr[node0 + tid] = excl;
        deg[node0 + tid] = v;
        ncur[tid] = excl;
    }
    __syncthreads();
    for (int j = tid; j < cnt; j += 256) {
        unsigned ed = ebuf[boff + j];
        int pos = atomicAdd(&ncur[ed >> 16], 1);
        csr_src[pos] = (int)(ed & 0xFFFF);
    }
}

// ---------------- aggregation kernel ----------------------------------------
// Wave per node, no LDS/barriers, 8 waves/SIMD.
// Lanes 0-31 cover edge 2k, lanes 32-63 edge 2k+1.
// C_IN==31: gathers precomputed {E=exp(t*x), P=x*E} half2 rows (128B = 1 line).
// C_IN==64: gathers y fp16 rows (128B = 1 line/edge, HALF the old 256B EP rows)
//           and computes E = exp2(t*log2e*y) in-loop (~2 v_exp per edge-pair,
//           ~3us/layer VALU vs ~halved line traffic on the gather floor).
// Output fp16 combined row aRowsB[d][0..63]:
//   C_IN==31: [aggr(31) | x(31) | 0 0],  C_IN==64: [aggr(64)].

template <int C_IN>
__global__ void __launch_bounds__(256, 8) aggr_kernel(
        const unsigned* __restrict__ EP, const unsigned short* __restrict__ xin,
        const float* __restrict__ tptr,
        const int* __restrict__ row_ptr, const int* __restrict__ deg,
        const int* __restrict__ csr_src,
        unsigned short* __restrict__ aRowsB, int n) {
    int w = threadIdx.x >> 6, l = threadIdx.x & 63;
    int d = blockIdx.x * 4 + w;
    if (d >= n) return;
    int beg = __builtin_amdgcn_readfirstlane(row_ptr[d]);
    int dg  = __builtin_amdgcn_readfirstlane(deg[d]);
    int end = beg + dg;
    int half = l >> 5;               // 0: edge 2k, 1: edge 2k+1

    if constexpr (C_IN == 64) {
        int co = l & 31;             // channel-pair index: ch 2co, 2co+1
        float t2 = tptr[0] * 1.44269504f;        // t * log2(e)
        const unsigned* Y = (const unsigned*)xin;  // fp16 rows: 32 dwords/row
        float2 num2 = {0.f, 0.f}, den2 = {0.f, 0.f};
        int base = beg;
        for (; base + 64 <= end; base += 64) {
            int sidx = csr_src[base + l];
            #pragma unroll
            for (int j = 0; j < 64; j += 16) {
                unsigned v[8];
                #pragma unroll
                for (int p = 0; p < 8; ++p) {
                    int sa = __builtin_amdgcn_readlane(sidx, j + 2 * p);
                    int sb = __builtin_amdgcn_readlane(sidx, j + 2 * p + 1);
                    int s  = half ? sb : sa;
                    v[p] = Y[(size_t)s * 32 + co];
                }
                #pragma unroll
                for (int p = 0; p < 8; ++p) {
                    float2 y = __half22float2(*(__half2*)&v[p]);
                    float E0 = exp2f(t2 * y.x);
                    float E1 = exp2f(t2 * y.y);
                    den2.x += E0; num2.x = fmaf(y.x, E0, num2.x);
                    den2.y += E1; num2.y = fmaf(y.y, E1, num2.y);
                }
            }
        }
        int rem = end - base;
        if (rem > 0) {
            int sidx = csr_src[base + ((l < rem) ? l : 0)];
            for (int j = 0; j < rem; j += 16) {
                unsigned v[8];
                #pragma unroll
                for (int p = 0; p < 8; ++p) {
                    int ja = j + 2 * p;     if (ja >= rem) ja = rem - 1;
                    int jb = j + 2 * p + 1; if (jb >= rem) jb = rem - 1;
                    int sa = __builtin_amdgcn_readlane(sidx, ja);
                    int sb = __builtin_amdgcn_readlane(sidx, jb);
                    int s  = half ? sb : sa;
                    v[p] = Y[(size_t)s * 32 + co];
                }
                #pragma unroll
                for (int p = 0; p < 8; ++p) {
                    float m = (j + 2 * p + half < rem) ? 1.f : 0.f;
                    float2 y = __half22float2(*(__half2*)&v[p]);
                    float E0 = exp2f(t2 * y.x);
                    float E1 = exp2f(t2 * y.y);
                    den2.x = fmaf(E0, m, den2.x); num2.x = fmaf(y.x * E0, m, num2.x);
                    den2.y = fmaf(E1, m, den2.y); num2.y = fmaf(y.y * E1, m, num2.y);
                }
            }
        }
        num2.x += __shfl_xor(num2.x, 32);
        num2.y += __shfl_xor(num2.y, 32);
        den2.x += __shfl_xor(den2.x, 32);
        den2.y += __shfl_xor(den2.y, 32);
        float nx = __shfl(num2.x, l >> 1);
        float ny = __shfl(num2.y, l >> 1);
        float dx = __shfl(den2.x, l >> 1);
        float dy = __shfl(den2.y, l >> 1);
        float num = (l & 1) ? ny : nx;
        float den = (l & 1) ? dy : dx;
        float aggr = (dg > 0 && den > 0.f) ? num / den : 0.f;
        aRowsB[(size_t)d * 64 + l] = f2h(aggr);
    } else {
        int ch = l & 31;
        int chc = (ch < C_IN) ? ch : (C_IN - 1);   // clamp for lanes 31,63
        float num = 0.f, den = 0.f;
        int base = beg;
        for (; base + 64 <= end; base += 64) {
            int sidx = csr_src[base + l];
            #pragma unroll
            for (int j = 0; j < 64; j += 16) {
                unsigned v[8];
                #pragma unroll
                for (int p = 0; p < 8; ++p) {
                    int sa = __builtin_amdgcn_readlane(sidx, j + 2 * p);
                    int sb = __builtin_amdgcn_readlane(sidx, j + 2 * p + 1);
                    int s  = half ? sb : sa;
                    v[p] = EP[(size_t)s * 32 + chc];
                }
                #pragma unroll
                for (int p = 0; p < 8; ++p) {
                    float2 e = unpackEP(v[p]);
                    den += e.x;
                    num += e.y;
                }
            }
        }
        int rem = end - base;
        if (rem > 0) {
            int sidx = csr_src[base + ((l < rem) ? l : 0)];
            for (int j = 0; j < rem; j += 16) {
                unsigned v[8];
                #pragma unroll
                for (int p = 0; p < 8; ++p) {
                    int ja = j + 2 * p;     if (ja >= rem) ja = rem - 1;
                    int jb = j + 2 * p + 1; if (jb >= rem) jb = rem - 1;
                    int sa = __builtin_amdgcn_readlane(sidx, ja);
                    int sb = __builtin_amdgcn_readlane(sidx, jb);
                    int s  = half ? sb : sa;
                    v[p] = EP[(size_t)s * 32 + chc];
                }
                #pragma unroll
                for (int p = 0; p < 8; ++p) {
                    float m = (j + 2 * p + half < rem) ? 1.f : 0.f;
                    float2 e = unpackEP(v[p]);
                    den = fmaf(e.x, m, den);
                    num = fmaf(e.y, m, num);
                }
            }
        }
        num += __shfl_xor(num, 32);
        den += __shfl_xor(den, 32);
        float aggr = (dg > 0 && den > 0.f) ? num / den : 0.f;
        unsigned short outv;
        if (l < C_IN)               outv = f2h(aggr);
        else if (l < 2 * C_IN)      outv = xin[(size_t)d * C_IN + (l - C_IN)];
        else                        outv = 0;
        aRowsB[(size_t)d * 64 + l] = outv;
    }
}

// ---------------- MFMA transform kernel (fp16, fused graph-max) -------------
// Y[64 x 64] = A[64 x K_TOT] @ W^T via mfma_f32_16x16x32_f16.
// Epilogue: instnorm/ReLU/store(yout fp16) + graph-max with wave-level
// pre-reduction (batch sorted: one 64-lane atomicMax per graph-run).
// EP epilogue removed: next layer gathers y directly and exps in-loop.

template <int C_IN, bool WY>
__global__ void __launch_bounds__(256, 4) transform_kernel(
        const unsigned short* __restrict__ aRowsB, const unsigned short* __restrict__ yprev,
        const int* __restrict__ batch,
        const float* __restrict__ Wr, const float* __restrict__ br,
        const float* __restrict__ Ws,
        unsigned short* __restrict__ yout,
        float* __restrict__ hmax, int n) {
    constexpr int K_TOT = (C_IN == 64) ? 128 : 64;
    constexpr int KP    = K_TOT + 8;
    constexpr int KS    = K_TOT / 32;
    constexpr int ABSH  = 2 * 64 * KP;
    constexpr int CSH   = 64 * 68 * 2;
    constexpr int SMSH  = (ABSH > CSH) ? ABSH : CSH;

    __shared__ short smem[SMSH];
    short* sA = smem;
    short* sB = smem + 64 * KP;
    float* sC = (float*)smem;              // overlays sA/sB after barrier

    int tid = threadIdx.x;
    int nb = blockIdx.x * 64;

    if constexpr (C_IN == 64) {
        for (int idx = tid; idx < 64 * 16; idx += 256) {      // A: aRowsB|yprev
            int row = idx >> 4, c8 = idx & 15;
            int node = nb + row; if (node >= n) node = n - 1;
            ushort8 v = (c8 < 8) ? ((const ushort8*)(aRowsB + (size_t)node * 64))[c8]
                                 : ((const ushort8*)(yprev + (size_t)node * 64))[c8 - 8];
            *(ushort8*)&sA[row * KP + c8 * 8] = v;
        }
        for (int idx = tid; idx < 64 * 32; idx += 256) {      // B: Wr|Ws rows
            int nr = idx >> 5, c4 = idx & 31;
            float4 v = (c4 < 16) ? ((const float4*)(Wr + nr * 64))[c4]
                                 : ((const float4*)(Ws + nr * 64))[c4 - 16];
            pack4h(&sB[nr * KP + c4 * 4], v);
        }
    } else {
        for (int idx = tid; idx < 64 * 8; idx += 256) {       // A: combined rows
            int row = idx >> 3, c8 = idx & 7;
            int node = nb + row; if (node >= n) node = n - 1;
            ushort8 v = ((const ushort8*)(aRowsB + (size_t)node * 64))[c8];
            *(ushort8*)&sA[row * KP + c8 * 8] = v;
        }
        for (int idx = tid; idx < 64 * 64; idx += 256) {      // B scalar (31 odd)
            int nr = idx >> 6, k = idx & 63;
            float v = (k < C_IN) ? Wr[nr * C_IN + k]
                    : (k < 2 * C_IN) ? Ws[nr * C_IN + (k - C_IN)] : 0.f;
            sB[nr * KP + k] = (short)f2h(v);
        }
    }
    __syncthreads();

    int w = tid >> 6, l = tid & 63;
    int m = l & 15;
    int q = l >> 4;
    floatx4 acc[4] = {{0.f,0.f,0.f,0.f},{0.f,0.f,0.f,0.f},
                      {0.f,0.f,0.f,0.f},{0.f,0.f,0.f,0.f}};
    const short* aBase = &sA[(w * 16 + m) * KP + q * 8];
    #pragma unroll 2
    for (int s = 0; s < KS; ++s) {
        half8 af = *(const half8*)(aBase + s * 32);
        #pragma unroll
        for (int t = 0; t < 4; ++t) {
            half8 bf = *(const half8*)&sB[(t * 16 + m) * KP + q * 8 + s * 32];
            acc[t] = __builtin_amdgcn_mfma_f32_16x16x32_f16(af, bf, acc[t], 0, 0, 0);
        }
    }

    __syncthreads();   // all mfma LDS reads done before sC overlays sA/sB
    #pragma unroll
    for (int t = 0; t < 4; ++t)
        #pragma unroll
        for (int r = 0; r < 4; ++r)
            sC[(w * 16 + q * 4 + r) * 68 + t * 16 + m] = acc[t][r];
    __syncthreads();

    float bias = br[l];
    int gcur = -1;
    float rmax = 0.f;
    for (int i = 0; i < 16; ++i) {
        int j = w * 16 + i;
        int d = nb + j;
        if (d < n) {                      // wave-uniform
            float a = sC[j * 68 + l] + bias;
            float s = a;
            for (int off = 32; off > 0; off >>= 1) s += __shfl_xor(s, off);
            float mu = s * (1.0f / 64.0f);
            float dc = a - mu;
            float s2 = dc * dc;
            for (int off = 32; off > 0; off >>= 1) s2 += __shfl_xor(s2, off);
            float var = s2 * (1.0f / 64.0f);
            float y = dc * rsqrtf(var + 1e-5f);
            y = fmaxf(y, 0.f);
            if constexpr (WY) {
                yout[(size_t)d * 64 + l] = f2h(y);
            }
            int g = __builtin_amdgcn_readfirstlane(batch[d]);  // sorted batch
            if (g != gcur) {
                if (gcur >= 0)
                    atomicMax((int*)&hmax[gcur * 64 + l], __float_as_int(rmax));
                gcur = g;
                rmax = 0.f;
            }
            rmax = fmaxf(rmax, y);
        }
    }
    if (gcur >= 0)   // y >= 0, hmax zero-init: int-punned max order-correct
        atomicMax((int*)&hmax[gcur * 64 + l], __float_as_int(rmax));
}

// ---------------- MLP head ----------------

__global__ void mlp_kernel(const float* __restrict__ h,  // [3][G][64]
                           const float* __restrict__ Wl1, const float* __restrict__ bl1,
                           const float* __restrict__ Wl2, const float* __restrict__ bl2,
                           float* __restrict__ out) {
    __shared__ float hrow[192];
    __shared__ float z1[128];
    __shared__ float z2[32];
    __shared__ float snorm;
    int g = blockIdx.x, tid = threadIdx.x;  // 128 threads
    if (tid < 64) {
        hrow[tid]       = h[0 * N_GRAPHS * 64 + g * 64 + tid];
        hrow[64 + tid]  = h[1 * N_GRAPHS * 64 + g * 64 + tid];
        hrow[128 + tid] = h[2 * N_GRAPHS * 64 + g * 64 + tid];
    }
    __syncthreads();
    float acc = bl1[tid];
    #pragma unroll 8
    for (int c = 0; c < 192; ++c) acc = fmaf(hrow[c], Wl1[tid * 192 + c], acc);
    z1[tid] = fmaxf(acc, 0.f);
    __syncthreads();
    if (tid < 32) {
        float a2 = bl2[tid];
        #pragma unroll 8
        for (int c = 0; c < 128; ++c) a2 = fmaf(z1[c], Wl2[tid * 128 + c], a2);
        z2[tid] = a2;
    }
    __syncthreads();
    if (tid == 0) {
        float ss = 0.f;
        for (int i = 0; i < 32; ++i) ss += z2[i] * z2[i];
        snorm = fmaxf(sqrtf(ss), 1e-12f);
    }
    __syncthreads();
    if (tid < 32) out[g * 32 + tid] = z2[tid] / snorm;
}

// ---------------- launch ----------------

extern "C" void kernel_launch(void* const* d_in, const int* in_sizes, int n_in,
                              void* d_out, int out_size, void* d_ws, size_t ws_size,
                              hipStream_t stream) {
    const float* x   = (const float*)d_in[0];
    const int* eidx  = (const int*)d_in[1];
    const int* batch = (const int*)d_in[2];
    const float* t   = (const float*)d_in[3];
    const float* W1r = (const float*)d_in[4];
    const float* b1  = (const float*)d_in[5];
    const float* W1s = (const float*)d_in[6];
    const float* W2r = (const float*)d_in[7];
    const float* b2  = (const float*)d_in[8];
    const float* W2s = (const float*)d_in[9];
    const float* W3r = (const float*)d_in[10];
    const float* b3  = (const float*)d_in[11];
    const float* W3s = (const float*)d_in[12];
    const float* Wl1 = (const float*)d_in[13];
    const float* bl1 = (const float*)d_in[14];
    const float* Wl2 = (const float*)d_in[15];
    const float* bl2 = (const float*)d_in[16];
    float* out = (float*)d_out;

    const int nE = in_sizes[1] / 2;
    const int nN = in_sizes[2];
    const int* src = eidx;
    const int* dst = eidx + nE;
    const int nb = (nN + 127) >> BKT_SHIFT;

    char* ws = (char*)d_ws;
    size_t off = 0;
    auto alloc = [&](size_t bytes) {
        char* p = ws + off;
        off = (off + bytes + 255) & ~(size_t)255;
        return p;
    };
    // bucket_cnt + h adjacent -> one zeroing memset
    int*            bucket_cnt = (int*)alloc((size_t)BKT_MAX * 4);
    float*          h          = (float*)alloc((size_t)3 * N_GRAPHS * 64 * 4);
    int*            row_ptr    = (int*)alloc((size_t)nN * 4);
    int*            deg        = (int*)alloc((size_t)nN * 4);
    unsigned*       ebuf       = (unsigned*)alloc((size_t)nb * CAP * 4);
    int*            csr_src    = (int*)alloc((size_t)nb * CAP * 4);
    unsigned short* xh         = (unsigned short*)alloc((size_t)nN * IN_CH * 2);
    unsigned*       EP0        = (unsigned*)alloc((size_t)nN * 32 * 4);
    unsigned short* yAh        = (unsigned short*)alloc((size_t)nN * 64 * 2);
    unsigned short* yBh        = (unsigned short*)alloc((size_t)nN * 64 * 2);
    unsigned short* aRowsB     = (unsigned short*)alloc((size_t)nN * 64 * 2);

    const int nbChunk = (nE + CHUNK - 1) / CHUNK;

    hipMemsetAsync(bucket_cnt, 0,
                   (char*)(h + 3 * N_GRAPHS * 64) - (char*)bucket_cnt, stream);
    prep_kernel<<<(nN * 32 + 255) / 256, 256, 0, stream>>>(x, t, xh, EP0, nN);
    bucket_scatter_kernel<<<nbChunk, 256, 0, stream>>>(src, dst, bucket_cnt, ebuf, nE, nb);
    bucket_csr_kernel<<<nb, 256, 0, stream>>>(ebuf, bucket_cnt, row_ptr, deg, csr_src, nN);

    const int nbA = (nN + 3) / 4;
    const int nbT = (nN + 63) / 64;

    aggr_kernel<IN_CH><<<nbA, 256, 0, stream>>>(EP0, xh, t, row_ptr, deg, csr_src, aRowsB, nN);
    transform_kernel<IN_CH, true><<<nbT, 256, 0, stream>>>(
        aRowsB, nullptr, batch, W1r, b1, W1s, yAh, h + 0 * N_GRAPHS * 64, nN);

    aggr_kernel<HID><<<nbA, 256, 0, stream>>>(nullptr, yAh, t, row_ptr, deg, csr_src, aRowsB, nN);
    transform_kernel<HID, true><<<nbT, 256, 0, stream>>>(
        aRowsB, yAh, batch, W2r, b2, W2s, yBh, h + 1 * N_GRAPHS * 64, nN);

    aggr_kernel<HID><<<nbA, 256, 0, stream>>>(nullptr, yBh, t, row_ptr, deg, csr_src, aRowsB, nN);
    transform_kernel<HID, false><<<nbT, 256, 0, stream>>>(
        aRowsB, yBh, batch, W3r, b3, W3s, nullptr, h + 2 * N_GRAPHS * 64, nN);

    mlp_kernel<<<N_GRAPHS, 128, 0, stream>>>(h, Wl1, bl1, Wl2, bl2, out);
}

// Round 2
// 270.139 us; speedup vs baseline: 1.0927x; 1.0927x over previous
//
#include <hip/hip_runtime.h>
#include <hip/hip_fp16.h>

#define N_NODES 50000
#define N_EDGES 800000
#define N_GRAPHS 128
#define IN_CH 31
#define HID 64

typedef __attribute__((ext_vector_type(8))) short short8;
typedef __attribute__((ext_vector_type(8))) unsigned short ushort8;
typedef __attribute__((ext_vector_type(4))) float floatx4;
typedef __attribute__((ext_vector_type(8))) _Float16 half8;
typedef __attribute__((ext_vector_type(2))) _Float16 half2v;

#if __has_builtin(__builtin_amdgcn_fdot2)
#define HAS_FDOT2 1
#endif

__device__ inline unsigned short f2h(float f) {          // fp32 -> fp16 bits
    __half h = __float2half_rn(f);
    return __half_as_ushort(h);
}
__device__ inline unsigned packh2(float a, float b) {    // half2 {a,b} bits
    __half2 h = __floats2half2_rn(a, b);
    return *(unsigned*)&h;
}
__device__ inline void pack4h(short* p, float4 v) {      // p 8B-aligned
    unsigned lo = packh2(v.x, v.y);
    unsigned hi = packh2(v.z, v.w);
    *(uint2*)p = make_uint2(lo, hi);
}
__device__ inline unsigned packEP(float E, float P) {    // half2 {E,P}
    return packh2(E, P);
}
__device__ inline float2 unpackEP(unsigned u) {
    __half2 h = *(__half2*)&u;
    return __half22float2(h);
}
__device__ inline half2v u2h2(unsigned u) {
    return __builtin_bit_cast(half2v, u);
}

// ---------------- prep: x -> xh (fp16) + EP0 (layer-1 softmax terms) --------
__global__ void prep_kernel(const float* __restrict__ x, const float* __restrict__ tptr,
                            unsigned short* __restrict__ xh, unsigned* __restrict__ EP0,
                            int nN) {
    int i = blockIdx.x * 256 + threadIdx.x;
    if (i >= nN * 32) return;
    int node = i >> 5, c = i & 31;
    if (c < IN_CH) {
        float xv = x[node * IN_CH + c];
        xh[node * IN_CH + c] = f2h(xv);
        float tval = tptr[0];
        float E = __expf(tval * xv);
        EP0[i] = packEP(E, xv * E);
    } else {
        EP0[i] = 0;
    }
}

// ---------------- CSR build: single-pass capacity-padded bucket sort --------
// Buckets of 128 nodes (dst>>7) with fixed capacity CAP: no global hist/scan
// (dst uniform-random: bucket mean 2046, CAP=2560 = +11 sigma).
// ebuf packs src (bits 0..15, N<65536) | local-dst (bits 16..22).

#define BKT_SHIFT 7
#define BKT_MAX 512
#define CHUNK 8192
#define CAP 2560

__global__ void bucket_scatter_kernel(const int* __restrict__ src,
                                      const int* __restrict__ dst,
                                      int* __restrict__ bucket_cnt,
                                      unsigned* __restrict__ ebuf, int e, int nb) {
    __shared__ int bins[BKT_MAX];
    __shared__ int base[BKT_MAX];
    __shared__ int lcur[BKT_MAX];
    int tid = threadIdx.x;
    int i0 = blockIdx.x * CHUNK;
    int i1 = i0 + CHUNK; if (i1 > e) i1 = e;
    for (int k = tid; k < nb; k += 256) { bins[k] = 0; lcur[k] = 0; }
    __syncthreads();
    for (int j = i0 + tid; j < i1; j += 256)
        atomicAdd(&bins[dst[j] >> BKT_SHIFT], 1);
    __syncthreads();
    for (int k = tid; k < nb; k += 256)
        if (bins[k]) base[k] = atomicAdd(&bucket_cnt[k], bins[k]);
    __syncthreads();
    for (int j = i0 + tid; j < i1; j += 256) {
        int ss = src[j], dd = dst[j];
        int b = dd >> BKT_SHIFT;
        int p = atomicAdd(&lcur[b], 1);
        ebuf[(size_t)b * CAP + base[b] + p] = (unsigned)ss | ((unsigned)(dd & 127) << 16);
    }
}

__global__ void bucket_csr_kernel(const unsigned* __restrict__ ebuf,
                                  const int* __restrict__ bucket_cnt,
                                  int* __restrict__ row_ptr, int* __restrict__ deg,
                                  int* __restrict__ csr_src, int nN) {
    __shared__ int nh[128];
    __shared__ int s[128];
    __shared__ int ncur[128];
    int tid = threadIdx.x;
    int b = blockIdx.x;
    int cnt = bucket_cnt[b];
    size_t boff = (size_t)b * CAP;
    int node0 = b << BKT_SHIFT;
    if (tid < 128) nh[tid] = 0;
    __syncthreads();
    for (int j = tid; j < cnt; j += 256)
        atomicAdd(&nh[ebuf[boff + j] >> 16], 1);
    __syncthreads();
    int v = (tid < 128) ? nh[tid] : 0;
    if (tid < 128) s[tid] = v;
    __syncthreads();
    for (int off = 1; off < 128; off <<= 1) {
        int u = (tid < 128 && tid >= off) ? s[tid - off] : 0;
        __syncthreads();
        if (tid < 128) s[tid] += u;
        __syncthreads();
    }
    if (tid < 128 && node0 + tid < nN) {
        int excl = (int)boff + s[tid] - v;
        row_ptr[node0 + tid] = excl;
        deg[node0 + tid] = v;
        ncur[tid] = excl;
    }
    __syncthreads();
    for (int j = tid; j < cnt; j += 256) {
        unsigned ed = ebuf[boff + j];
        int pos = atomicAdd(&ncur[ed >> 16], 1);
        csr_src[pos] = (int)(ed & 0xFFFF);
    }
}

// ---------------- aggregation kernel ----------------------------------------
// Wave per node, no LDS/barriers. ONE EDGE PER STEP, lane = channel:
//   EP row (node s) = ROWD dwords of half2{E=exp(t*v), P=v*E}; all 64 lanes
//   load one dword of the SAME row (SGPR base via readlane -> SALU addressing,
//   no divergent address select). Accumulate with v_dot2_f32_f16:
//   den += E  (b={1,0}), num += P  (b={0,1}) -> 2 VALU/edge/lane vs 4 cvt+add.
//   No cross-lane redistribution at the end: lane l holds channel l.
// r1 lesson (measured): aggr is VALU-issue sensitive (exp-in-loop cost
// +10us/layer at VALUBusy 75%), NOT gather-byte bound (halving row bytes
// did not help; HBM 11%). So: precomputed EP + minimum per-edge VALU.
// Remainder: uniform live-mask via SALU-selected dot-b operand (dup loads
// of edge chunk-1 contribute 0).

template <int C_IN>
__global__ void __launch_bounds__(256, 8) aggr_kernel(
        const unsigned* __restrict__ EP, const unsigned short* __restrict__ xin,
        const int* __restrict__ row_ptr, const int* __restrict__ deg,
        const int* __restrict__ csr_src,
        unsigned short* __restrict__ aRowsB, int n) {
    constexpr int ROWD = (C_IN == 64) ? 64 : 32;   // dwords per EP row
    int w = threadIdx.x >> 6, l = threadIdx.x & 63;
    int d = blockIdx.x * 4 + w;
    if (d >= n) return;
    int beg = __builtin_amdgcn_readfirstlane(row_ptr[d]);
    int dg  = __builtin_amdgcn_readfirstlane(deg[d]);
    int end = beg + dg;
    int cl = l & (ROWD - 1);

    float den0 = 0.f, den1 = 0.f, num0 = 0.f, num1 = 0.f;
    for (int base = beg; base < end; base += 64) {
        int cend = base + 64; if (cend > end) cend = end;
        int chunk = cend - base;                       // uniform, 1..64
        int sidx = csr_src[base + ((l < chunk) ? l : 0)];
        for (int j0 = 0; j0 < chunk; j0 += 8) {
            int jc = chunk - j0;                       // uniform, >=1
            unsigned v[8];
            #pragma unroll
            for (int p = 0; p < 8; ++p) {
                int jj = (p < jc) ? (j0 + p) : (chunk - 1);   // uniform clamp
                int s  = __builtin_amdgcn_readlane(sidx, jj); // SGPR row id
                v[p] = EP[(size_t)s * ROWD + cl];
            }
            #pragma unroll
            for (int p = 0; p < 8; ++p) {
                bool live = (p < jc);                  // uniform
#ifdef HAS_FDOT2
                unsigned bE = live ? 0x00003C00u : 0u;   // half2{1,0}
                unsigned bP = live ? 0x3C000000u : 0u;   // half2{0,1}
                if (p & 1) {
                    den1 = __builtin_amdgcn_fdot2(u2h2(v[p]), u2h2(bE), den1, false);
                    num1 = __builtin_amdgcn_fdot2(u2h2(v[p]), u2h2(bP), num1, false);
                } else {
                    den0 = __builtin_amdgcn_fdot2(u2h2(v[p]), u2h2(bE), den0, false);
                    num0 = __builtin_amdgcn_fdot2(u2h2(v[p]), u2h2(bP), num0, false);
                }
#else
                float mm = live ? 1.f : 0.f;
                float2 e = unpackEP(v[p]);
                if (p & 1) {
                    den1 = fmaf(e.x, mm, den1); num1 = fmaf(e.y, mm, num1);
                } else {
                    den0 = fmaf(e.x, mm, den0); num0 = fmaf(e.y, mm, num0);
                }
#endif
            }
        }
    }
    float den = den0 + den1;
    float num = num0 + num1;
    float aggr = (dg > 0 && den > 0.f) ? num / den : 0.f;

    if constexpr (C_IN == 64) {
        aRowsB[(size_t)d * 64 + l] = f2h(aggr);
    } else {
        unsigned short outv;
        if (l < C_IN)               outv = f2h(aggr);
        else if (l < 2 * C_IN)      outv = xin[(size_t)d * C_IN + (l - C_IN)];
        else                        outv = 0;
        aRowsB[(size_t)d * 64 + l] = outv;
    }
}

// ---------------- MFMA transform kernel (fp16, fused EP + graph-max) --------
// Y[64 x 64] = A[64 x K_TOT] @ W^T via mfma_f32_16x16x32_f16.
// Epilogue: instnorm/ReLU/store(yout fp16) + (WEP) next-layer EP half2 rows +
// graph-max with wave-level pre-reduction (batch sorted: one 64-lane
// atomicMax per graph-run).

template <int C_IN, bool WEP>
__global__ void __launch_bounds__(256, 4) transform_kernel(
        const unsigned short* __restrict__ aRowsB, const unsigned short* __restrict__ yprev,
        const int* __restrict__ batch,
        const float* __restrict__ Wr, const float* __restrict__ br,
        const float* __restrict__ Ws, const float* __restrict__ tptr,
        unsigned short* __restrict__ yout, unsigned* __restrict__ EPout,
        float* __restrict__ hmax, int n) {
    constexpr int K_TOT = (C_IN == 64) ? 128 : 64;
    constexpr int KP    = K_TOT + 8;
    constexpr int KS    = K_TOT / 32;
    constexpr int ABSH  = 2 * 64 * KP;
    constexpr int CSH   = 64 * 68 * 2;
    constexpr int SMSH  = (ABSH > CSH) ? ABSH : CSH;

    __shared__ short smem[SMSH];
    short* sA = smem;
    short* sB = smem + 64 * KP;
    float* sC = (float*)smem;              // overlays sA/sB after barrier

    int tid = threadIdx.x;
    int nb = blockIdx.x * 64;

    if constexpr (C_IN == 64) {
        for (int idx = tid; idx < 64 * 16; idx += 256) {      // A: aRowsB|yprev
            int row = idx >> 4, c8 = idx & 15;
            int node = nb + row; if (node >= n) node = n - 1;
            ushort8 v = (c8 < 8) ? ((const ushort8*)(aRowsB + (size_t)node * 64))[c8]
                                 : ((const ushort8*)(yprev + (size_t)node * 64))[c8 - 8];
            *(ushort8*)&sA[row * KP + c8 * 8] = v;
        }
        for (int idx = tid; idx < 64 * 32; idx += 256) {      // B: Wr|Ws rows
            int nr = idx >> 5, c4 = idx & 31;
            float4 v = (c4 < 16) ? ((const float4*)(Wr + nr * 64))[c4]
                                 : ((const float4*)(Ws + nr * 64))[c4 - 16];
            pack4h(&sB[nr * KP + c4 * 4], v);
        }
    } else {
        for (int idx = tid; idx < 64 * 8; idx += 256) {       // A: combined rows
            int row = idx >> 3, c8 = idx & 7;
            int node = nb + row; if (node >= n) node = n - 1;
            ushort8 v = ((const ushort8*)(aRowsB + (size_t)node * 64))[c8];
            *(ushort8*)&sA[row * KP + c8 * 8] = v;
        }
        for (int idx = tid; idx < 64 * 64; idx += 256) {      // B scalar (31 odd)
            int nr = idx >> 6, k = idx & 63;
            float v = (k < C_IN) ? Wr[nr * C_IN + k]
                    : (k < 2 * C_IN) ? Ws[nr * C_IN + (k - C_IN)] : 0.f;
            sB[nr * KP + k] = (short)f2h(v);
        }
    }
    __syncthreads();

    int w = tid >> 6, l = tid & 63;
    int m = l & 15;
    int q = l >> 4;
    floatx4 acc[4] = {{0.f,0.f,0.f,0.f},{0.f,0.f,0.f,0.f},
                      {0.f,0.f,0.f,0.f},{0.f,0.f,0.f,0.f}};
    const short* aBase = &sA[(w * 16 + m) * KP + q * 8];
    #pragma unroll 2
    for (int s = 0; s < KS; ++s) {
        half8 af = *(const half8*)(aBase + s * 32);
        #pragma unroll
        for (int t = 0; t < 4; ++t) {
            half8 bf = *(const half8*)&sB[(t * 16 + m) * KP + q * 8 + s * 32];
            acc[t] = __builtin_amdgcn_mfma_f32_16x16x32_f16(af, bf, acc[t], 0, 0, 0);
        }
    }

    __syncthreads();   // all mfma LDS reads done before sC overlays sA/sB
    #pragma unroll
    for (int t = 0; t < 4; ++t)
        #pragma unroll
        for (int r = 0; r < 4; ++r)
            sC[(w * 16 + q * 4 + r) * 68 + t * 16 + m] = acc[t][r];
    __syncthreads();

    float bias = br[l];
    float tval = 0.f;
    if constexpr (WEP) tval = tptr[0];
    int gcur = -1;
    float rmax = 0.f;
    for (int i = 0; i < 16; ++i) {
        int j = w * 16 + i;
        int d = nb + j;
        if (d < n) {                      // wave-uniform
            float a = sC[j * 68 + l] + bias;
            float s = a;
            for (int off = 32; off > 0; off >>= 1) s += __shfl_xor(s, off);
            float mu = s * (1.0f / 64.0f);
            float dc = a - mu;
            float s2 = dc * dc;
            for (int off = 32; off > 0; off >>= 1) s2 += __shfl_xor(s2, off);
            float var = s2 * (1.0f / 64.0f);
            float y = dc * rsqrtf(var + 1e-5f);
            y = fmaxf(y, 0.f);
            if constexpr (WEP) {
                yout[(size_t)d * 64 + l] = f2h(y);
                float E = __expf(tval * y);
                EPout[(size_t)d * 64 + l] = packEP(E, y * E);
            }
            int g = __builtin_amdgcn_readfirstlane(batch[d]);  // sorted batch
            if (g != gcur) {
                if (gcur >= 0)
                    atomicMax((int*)&hmax[gcur * 64 + l], __float_as_int(rmax));
                gcur = g;
                rmax = 0.f;
            }
            rmax = fmaxf(rmax, y);
        }
    }
    if (gcur >= 0)   // y >= 0, hmax zero-init: int-punned max order-correct
        atomicMax((int*)&hmax[gcur * 64 + l], __float_as_int(rmax));
}

// ---------------- MLP head ----------------

__global__ void mlp_kernel(const float* __restrict__ h,  // [3][G][64]
                           const float* __restrict__ Wl1, const float* __restrict__ bl1,
                           const float* __restrict__ Wl2, const float* __restrict__ bl2,
                           float* __restrict__ out) {
    __shared__ float hrow[192];
    __shared__ float z1[128];
    __shared__ float z2[32];
    __shared__ float snorm;
    int g = blockIdx.x, tid = threadIdx.x;  // 128 threads
    if (tid < 64) {
        hrow[tid]       = h[0 * N_GRAPHS * 64 + g * 64 + tid];
        hrow[64 + tid]  = h[1 * N_GRAPHS * 64 + g * 64 + tid];
        hrow[128 + tid] = h[2 * N_GRAPHS * 64 + g * 64 + tid];
    }
    __syncthreads();
    float acc = bl1[tid];
    #pragma unroll 8
    for (int c = 0; c < 192; ++c) acc = fmaf(hrow[c], Wl1[tid * 192 + c], acc);
    z1[tid] = fmaxf(acc, 0.f);
    __syncthreads();
    if (tid < 32) {
        float a2 = bl2[tid];
        #pragma unroll 8
        for (int c = 0; c < 128; ++c) a2 = fmaf(z1[c], Wl2[tid * 128 + c], a2);
        z2[tid] = a2;
    }
    __syncthreads();
    if (tid == 0) {
        float ss = 0.f;
        for (int i = 0; i < 32; ++i) ss += z2[i] * z2[i];
        snorm = fmaxf(sqrtf(ss), 1e-12f);
    }
    __syncthreads();
    if (tid < 32) out[g * 32 + tid] = z2[tid] / snorm;
}

// ---------------- launch ----------------

extern "C" void kernel_launch(void* const* d_in, const int* in_sizes, int n_in,
                              void* d_out, int out_size, void* d_ws, size_t ws_size,
                              hipStream_t stream) {
    const float* x   = (const float*)d_in[0];
    const int* eidx  = (const int*)d_in[1];
    const int* batch = (const int*)d_in[2];
    const float* t   = (const float*)d_in[3];
    const float* W1r = (const float*)d_in[4];
    const float* b1  = (const float*)d_in[5];
    const float* W1s = (const float*)d_in[6];
    const float* W2r = (const float*)d_in[7];
    const float* b2  = (const float*)d_in[8];
    const float* W2s = (const float*)d_in[9];
    const float* W3r = (const float*)d_in[10];
    const float* b3  = (const float*)d_in[11];
    const float* W3s = (const float*)d_in[12];
    const float* Wl1 = (const float*)d_in[13];
    const float* bl1 = (const float*)d_in[14];
    const float* Wl2 = (const float*)d_in[15];
    const float* bl2 = (const float*)d_in[16];
    float* out = (float*)d_out;

    const int nE = in_sizes[1] / 2;
    const int nN = in_sizes[2];
    const int* src = eidx;
    const int* dst = eidx + nE;
    const int nb = (nN + 127) >> BKT_SHIFT;

    char* ws = (char*)d_ws;
    size_t off = 0;
    auto alloc = [&](size_t bytes) {
        char* p = ws + off;
        off = (off + bytes + 255) & ~(size_t)255;
        return p;
    };
    // bucket_cnt + h adjacent -> one zeroing memset
    int*            bucket_cnt = (int*)alloc((size_t)BKT_MAX * 4);
    float*          h          = (float*)alloc((size_t)3 * N_GRAPHS * 64 * 4);
    int*            row_ptr    = (int*)alloc((size_t)nN * 4);
    int*            deg        = (int*)alloc((size_t)nN * 4);
    unsigned*       ebuf       = (unsigned*)alloc((size_t)nb * CAP * 4);
    int*            csr_src    = (int*)alloc((size_t)nb * CAP * 4);
    unsigned short* xh         = (unsigned short*)alloc((size_t)nN * IN_CH * 2);
    unsigned*       EP0        = (unsigned*)alloc((size_t)nN * 32 * 4);
    unsigned*       EPA        = (unsigned*)alloc((size_t)nN * 64 * 4);
    unsigned*       EPB        = (unsigned*)alloc((size_t)nN * 64 * 4);
    unsigned short* yAh        = (unsigned short*)alloc((size_t)nN * 64 * 2);
    unsigned short* yBh        = (unsigned short*)alloc((size_t)nN * 64 * 2);
    unsigned short* aRowsB     = (unsigned short*)alloc((size_t)nN * 64 * 2);

    const int nbChunk = (nE + CHUNK - 1) / CHUNK;

    hipMemsetAsync(bucket_cnt, 0,
                   (char*)(h + 3 * N_GRAPHS * 64) - (char*)bucket_cnt, stream);
    prep_kernel<<<(nN * 32 + 255) / 256, 256, 0, stream>>>(x, t, xh, EP0, nN);
    bucket_scatter_kernel<<<nbChunk, 256, 0, stream>>>(src, dst, bucket_cnt, ebuf, nE, nb);
    bucket_csr_kernel<<<nb, 256, 0, stream>>>(ebuf, bucket_cnt, row_ptr, deg, csr_src, nN);

    const int nbA = (nN + 3) / 4;
    const int nbT = (nN + 63) / 64;

    aggr_kernel<IN_CH><<<nbA, 256, 0, stream>>>(EP0, xh, row_ptr, deg, csr_src, aRowsB, nN);
    transform_kernel<IN_CH, true><<<nbT, 256, 0, stream>>>(
        aRowsB, nullptr, batch, W1r, b1, W1s, t, yAh, EPA, h + 0 * N_GRAPHS * 64, nN);

    aggr_kernel<HID><<<nbA, 256, 0, stream>>>(EPA, nullptr, row_ptr, deg, csr_src, aRowsB, nN);
    transform_kernel<HID, true><<<nbT, 256, 0, stream>>>(
        aRowsB, yAh, batch, W2r, b2, W2s, t, yBh, EPB, h + 1 * N_GRAPHS * 64, nN);

    aggr_kernel<HID><<<nbA, 256, 0, stream>>>(EPB, nullptr, row_ptr, deg, csr_src, aRowsB, nN);
    transform_kernel<HID, false><<<nbT, 256, 0, stream>>>(
        aRowsB, yBh, batch, W3r, b3, W3s, t, nullptr, nullptr, h + 2 * N_GRAPHS * 64, nN);

    mlp_kernel<<<N_GRAPHS, 128, 0, stream>>>(h, Wl1, bl1, Wl2, bl2, out);
}

// Round 3
// 266.598 us; speedup vs baseline: 1.1072x; 1.0133x over previous
//
#include <hip/hip_runtime.h>
#include <hip/hip_fp16.h>

#define N_NODES 50000
#define N_EDGES 800000
#define N_GRAPHS 128
#define IN_CH 31
#define HID 64

typedef __attribute__((ext_vector_type(8))) short short8;
typedef __attribute__((ext_vector_type(8))) unsigned short ushort8;
typedef __attribute__((ext_vector_type(4))) float floatx4;
typedef __attribute__((ext_vector_type(8))) _Float16 half8;

__device__ inline unsigned short f2h(float f) {          // fp32 -> fp16 bits
    __half h = __float2half_rn(f);
    return __half_as_ushort(h);
}
__device__ inline unsigned packh2(float a, float b) {    // half2 {a,b} bits
    __half2 h = __floats2half2_rn(a, b);
    return *(unsigned*)&h;
}
__device__ inline void pack4h(short* p, float4 v) {      // p 8B-aligned
    unsigned lo = packh2(v.x, v.y);
    unsigned hi = packh2(v.z, v.w);
    *(uint2*)p = make_uint2(lo, hi);
}

// ---------------- prep: x -> padded fp16 rows xh32 [nN][32] -----------------
// 3.2MB table: fits per-XCD L2 (4MB) -> layer-1 gather is L2-resident.
__global__ void prep_kernel(const float* __restrict__ x,
                            unsigned short* __restrict__ xh32, int nN) {
    int i = blockIdx.x * 256 + threadIdx.x;
    if (i >= nN * 32) return;
    int node = i >> 5, c = i & 31;
    xh32[i] = (c < IN_CH) ? f2h(x[node * IN_CH + c]) : 0;
}

// ---------------- CSR build: single-pass capacity-padded bucket sort --------
// Buckets of 128 nodes (dst>>7) with fixed capacity CAP: no global hist/scan
// (dst uniform-random: bucket mean 2046, CAP=2560 = +11 sigma).
// ebuf packs src (bits 0..15, N<65536) | local-dst (bits 16..22).

#define BKT_SHIFT 7
#define BKT_MAX 512
#define CHUNK 8192
#define CAP 2560

__global__ void bucket_scatter_kernel(const int* __restrict__ src,
                                      const int* __restrict__ dst,
                                      int* __restrict__ bucket_cnt,
                                      unsigned* __restrict__ ebuf, int e, int nb) {
    __shared__ int bins[BKT_MAX];
    __shared__ int base[BKT_MAX];
    __shared__ int lcur[BKT_MAX];
    int tid = threadIdx.x;
    int i0 = blockIdx.x * CHUNK;
    int i1 = i0 + CHUNK; if (i1 > e) i1 = e;
    for (int k = tid; k < nb; k += 256) { bins[k] = 0; lcur[k] = 0; }
    __syncthreads();
    for (int j = i0 + tid; j < i1; j += 256)
        atomicAdd(&bins[dst[j] >> BKT_SHIFT], 1);
    __syncthreads();
    for (int k = tid; k < nb; k += 256)
        if (bins[k]) base[k] = atomicAdd(&bucket_cnt[k], bins[k]);
    __syncthreads();
    for (int j = i0 + tid; j < i1; j += 256) {
        int ss = src[j], dd = dst[j];
        int b = dd >> BKT_SHIFT;
        int p = atomicAdd(&lcur[b], 1);
        ebuf[(size_t)b * CAP + base[b] + p] = (unsigned)ss | ((unsigned)(dd & 127) << 16);
    }
}

__global__ void bucket_csr_kernel(const unsigned* __restrict__ ebuf,
                                  const int* __restrict__ bucket_cnt,
                                  int* __restrict__ row_ptr, int* __restrict__ deg,
                                  int* __restrict__ csr_src, int nN) {
    __shared__ int nh[128];
    __shared__ int s[128];
    __shared__ int ncur[128];
    int tid = threadIdx.x;
    int b = blockIdx.x;
    int cnt = bucket_cnt[b];
    size_t boff = (size_t)b * CAP;
    int node0 = b << BKT_SHIFT;
    if (tid < 128) nh[tid] = 0;
    __syncthreads();
    for (int j = tid; j < cnt; j += 256)
        atomicAdd(&nh[ebuf[boff + j] >> 16], 1);
    __syncthreads();
    int v = (tid < 128) ? nh[tid] : 0;
    if (tid < 128) s[tid] = v;
    __syncthreads();
    for (int off = 1; off < 128; off <<= 1) {
        int u = (tid < 128 && tid >= off) ? s[tid - off] : 0;
        __syncthreads();
        if (tid < 128) s[tid] += u;
        __syncthreads();
    }
    if (tid < 128 && node0 + tid < nN) {
        int excl = (int)boff + s[tid] - v;
        row_ptr[node0 + tid] = excl;
        deg[node0 + tid] = v;
        ncur[tid] = excl;
    }
    __syncthreads();
    for (int j = tid; j < cnt; j += 256) {
        unsigned ed = ebuf[boff + j];
        int pos = atomicAdd(&ncur[ed >> 16], 1);
        csr_src[pos] = (int)(ed & 0xFFFF);
    }
}

// ---------------- aggregation kernel ----------------------------------------
// Wave per node, no LDS/barriers. ONE EDGE PER STEP, lane = channel.
// Gathers fp16 y rows DIRECTLY (128B = 1 line/edge; half the EP-row bytes)
// and computes E = exp(t*y) in-loop (v_exp on trans pipe, co-issues).
// SGPR row base via readlane: no per-lane address math.
// Rationale (measured r1/r2): r1's byte-halving null was at VALUBusy 75%
// (VALU-masked); r2's lean loop dropped VALU ~4x -> gather is now
// L2-capacity / L3-random-BW bound (12.8MB EP table vs 4MB per-XCD L2).
// y-table = 6.4MB (HID) / 3.2MB (layer-1, L2-RESIDENT): halves logical bytes
// AND roughly doubles L2 hit rate -> ~3.5x less L3-side traffic.

template <int C_IN>
__global__ void __launch_bounds__(256, 8) aggr_kernel(
        const unsigned short* __restrict__ Ytab,   // fp16 rows, RS ushorts/row
        const float* __restrict__ tptr,
        const int* __restrict__ row_ptr, const int* __restrict__ deg,
        const int* __restrict__ csr_src,
        unsigned short* __restrict__ aRowsB, int n) {
    constexpr int RS = (C_IN == 64) ? 64 : 32;     // row stride (ushorts)
    int w = threadIdx.x >> 6, l = threadIdx.x & 63;
    int d = blockIdx.x * 4 + w;
    if (d >= n) return;
    int beg = __builtin_amdgcn_readfirstlane(row_ptr[d]);
    int dg  = __builtin_amdgcn_readfirstlane(deg[d]);
    int end = beg + dg;
    int cl = l & (RS - 1);
    float tval = tptr[0];

    float den = 0.f, num = 0.f;
    for (int base = beg; base < end; base += 64) {
        int cend = base + 64; if (cend > end) cend = end;
        int chunk = cend - base;                       // uniform, 1..64
        int sidx = csr_src[base + ((l < chunk) ? l : 0)];
        for (int j0 = 0; j0 < chunk; j0 += 8) {
            int jc = chunk - j0;                       // uniform, >=1
            float yv[8];
            #pragma unroll
            for (int p = 0; p < 8; ++p) {
                int jj = (p < jc) ? (j0 + p) : (chunk - 1);   // uniform clamp
                int s  = __builtin_amdgcn_readlane(sidx, jj); // SGPR row id
                yv[p] = (float)*(const _Float16*)&Ytab[(size_t)s * RS + cl];
            }
            #pragma unroll
            for (int p = 0; p < 8; ++p) {
                float m = (p < jc) ? 1.f : 0.f;        // uniform live-mask
                float E = __expf(tval * yv[p]) * m;
                den += E;
                num = fmaf(yv[p], E, num);
            }
        }
    }
    float aggr = (dg > 0 && den > 0.f) ? num / den : 0.f;

    if constexpr (C_IN == 64) {
        aRowsB[(size_t)d * 64 + l] = f2h(aggr);
    } else {
        unsigned short outv;
        if (l < C_IN)               outv = f2h(aggr);
        else if (l < 2 * C_IN)      outv = Ytab[(size_t)d * 32 + (l - C_IN)];
        else                        outv = 0;
        aRowsB[(size_t)d * 64 + l] = outv;
    }
}

// ---------------- MFMA transform kernel (fp16, fused graph-max) -------------
// Y[64 x 64] = A[64 x K_TOT] @ W^T via mfma_f32_16x16x32_f16.
// Epilogue: instnorm/ReLU/store(yout fp16) + graph-max with wave-level
// pre-reduction (batch sorted: one 64-lane atomicMax per graph-run).
// EP epilogue removed: next layer gathers y directly, exp in-loop.

template <int C_IN, bool WY>
__global__ void __launch_bounds__(256, 4) transform_kernel(
        const unsigned short* __restrict__ aRowsB, const unsigned short* __restrict__ yprev,
        const int* __restrict__ batch,
        const float* __restrict__ Wr, const float* __restrict__ br,
        const float* __restrict__ Ws,
        unsigned short* __restrict__ yout,
        float* __restrict__ hmax, int n) {
    constexpr int K_TOT = (C_IN == 64) ? 128 : 64;
    constexpr int KP    = K_TOT + 8;
    constexpr int KS    = K_TOT / 32;
    constexpr int ABSH  = 2 * 64 * KP;
    constexpr int CSH   = 64 * 68 * 2;
    constexpr int SMSH  = (ABSH > CSH) ? ABSH : CSH;

    __shared__ short smem[SMSH];
    short* sA = smem;
    short* sB = smem + 64 * KP;
    float* sC = (float*)smem;              // overlays sA/sB after barrier

    int tid = threadIdx.x;
    int nb = blockIdx.x * 64;

    if constexpr (C_IN == 64) {
        for (int idx = tid; idx < 64 * 16; idx += 256) {      // A: aRowsB|yprev
            int row = idx >> 4, c8 = idx & 15;
            int node = nb + row; if (node >= n) node = n - 1;
            ushort8 v = (c8 < 8) ? ((const ushort8*)(aRowsB + (size_t)node * 64))[c8]
                                 : ((const ushort8*)(yprev + (size_t)node * 64))[c8 - 8];
            *(ushort8*)&sA[row * KP + c8 * 8] = v;
        }
        for (int idx = tid; idx < 64 * 32; idx += 256) {      // B: Wr|Ws rows
            int nr = idx >> 5, c4 = idx & 31;
            float4 v = (c4 < 16) ? ((const float4*)(Wr + nr * 64))[c4]
                                 : ((const float4*)(Ws + nr * 64))[c4 - 16];
            pack4h(&sB[nr * KP + c4 * 4], v);
        }
    } else {
        for (int idx = tid; idx < 64 * 8; idx += 256) {       // A: combined rows
            int row = idx >> 3, c8 = idx & 7;
            int node = nb + row; if (node >= n) node = n - 1;
            ushort8 v = ((const ushort8*)(aRowsB + (size_t)node * 64))[c8];
            *(ushort8*)&sA[row * KP + c8 * 8] = v;
        }
        for (int idx = tid; idx < 64 * 64; idx += 256) {      // B scalar (31 odd)
            int nr = idx >> 6, k = idx & 63;
            float v = (k < C_IN) ? Wr[nr * C_IN + k]
                    : (k < 2 * C_IN) ? Ws[nr * C_IN + (k - C_IN)] : 0.f;
            sB[nr * KP + k] = (short)f2h(v);
        }
    }
    __syncthreads();

    int w = tid >> 6, l = tid & 63;
    int m = l & 15;
    int q = l >> 4;
    floatx4 acc[4] = {{0.f,0.f,0.f,0.f},{0.f,0.f,0.f,0.f},
                      {0.f,0.f,0.f,0.f},{0.f,0.f,0.f,0.f}};
    const short* aBase = &sA[(w * 16 + m) * KP + q * 8];
    #pragma unroll 2
    for (int s = 0; s < KS; ++s) {
        half8 af = *(const half8*)(aBase + s * 32);
        #pragma unroll
        for (int t = 0; t < 4; ++t) {
            half8 bf = *(const half8*)&sB[(t * 16 + m) * KP + q * 8 + s * 32];
            acc[t] = __builtin_amdgcn_mfma_f32_16x16x32_f16(af, bf, acc[t], 0, 0, 0);
        }
    }

    __syncthreads();   // all mfma LDS reads done before sC overlays sA/sB
    #pragma unroll
    for (int t = 0; t < 4; ++t)
        #pragma unroll
        for (int r = 0; r < 4; ++r)
            sC[(w * 16 + q * 4 + r) * 68 + t * 16 + m] = acc[t][r];
    __syncthreads();

    float bias = br[l];
    int gcur = -1;
    float rmax = 0.f;
    for (int i = 0; i < 16; ++i) {
        int j = w * 16 + i;
        int d = nb + j;
        if (d < n) {                      // wave-uniform
            float a = sC[j * 68 + l] + bias;
            float s = a;
            for (int off = 32; off > 0; off >>= 1) s += __shfl_xor(s, off);
            float mu = s * (1.0f / 64.0f);
            float dc = a - mu;
            float s2 = dc * dc;
            for (int off = 32; off > 0; off >>= 1) s2 += __shfl_xor(s2, off);
            float var = s2 * (1.0f / 64.0f);
            float y = dc * rsqrtf(var + 1e-5f);
            y = fmaxf(y, 0.f);
            if constexpr (WY) {
                yout[(size_t)d * 64 + l] = f2h(y);
            }
            int g = __builtin_amdgcn_readfirstlane(batch[d]);  // sorted batch
            if (g != gcur) {
                if (gcur >= 0)
                    atomicMax((int*)&hmax[gcur * 64 + l], __float_as_int(rmax));
                gcur = g;
                rmax = 0.f;
            }
            rmax = fmaxf(rmax, y);
        }
    }
    if (gcur >= 0)   // y >= 0, hmax zero-init: int-punned max order-correct
        atomicMax((int*)&hmax[gcur * 64 + l], __float_as_int(rmax));
}

// ---------------- MLP head ----------------

__global__ void mlp_kernel(const float* __restrict__ h,  // [3][G][64]
                           const float* __restrict__ Wl1, const float* __restrict__ bl1,
                           const float* __restrict__ Wl2, const float* __restrict__ bl2,
                           float* __restrict__ out) {
    __shared__ float hrow[192];
    __shared__ float z1[128];
    __shared__ float z2[32];
    __shared__ float snorm;
    int g = blockIdx.x, tid = threadIdx.x;  // 128 threads
    if (tid < 64) {
        hrow[tid]       = h[0 * N_GRAPHS * 64 + g * 64 + tid];
        hrow[64 + tid]  = h[1 * N_GRAPHS * 64 + g * 64 + tid];
        hrow[128 + tid] = h[2 * N_GRAPHS * 64 + g * 64 + tid];
    }
    __syncthreads();
    float acc = bl1[tid];
    #pragma unroll 8
    for (int c = 0; c < 192; ++c) acc = fmaf(hrow[c], Wl1[tid * 192 + c], acc);
    z1[tid] = fmaxf(acc, 0.f);
    __syncthreads();
    if (tid < 32) {
        float a2 = bl2[tid];
        #pragma unroll 8
        for (int c = 0; c < 128; ++c) a2 = fmaf(z1[c], Wl2[tid * 128 + c], a2);
        z2[tid] = a2;
    }
    __syncthreads();
    if (tid == 0) {
        float ss = 0.f;
        for (int i = 0; i < 32; ++i) ss += z2[i] * z2[i];
        snorm = fmaxf(sqrtf(ss), 1e-12f);
    }
    __syncthreads();
    if (tid < 32) out[g * 32 + tid] = z2[tid] / snorm;
}

// ---------------- launch ----------------

extern "C" void kernel_launch(void* const* d_in, const int* in_sizes, int n_in,
                              void* d_out, int out_size, void* d_ws, size_t ws_size,
                              hipStream_t stream) {
    const float* x   = (const float*)d_in[0];
    const int* eidx  = (const int*)d_in[1];
    const int* batch = (const int*)d_in[2];
    const float* t   = (const float*)d_in[3];
    const float* W1r = (const float*)d_in[4];
    const float* b1  = (const float*)d_in[5];
    const float* W1s = (const float*)d_in[6];
    const float* W2r = (const float*)d_in[7];
    const float* b2  = (const float*)d_in[8];
    const float* W2s = (const float*)d_in[9];
    const float* W3r = (const float*)d_in[10];
    const float* b3  = (const float*)d_in[11];
    const float* W3s = (const float*)d_in[12];
    const float* Wl1 = (const float*)d_in[13];
    const float* bl1 = (const float*)d_in[14];
    const float* Wl2 = (const float*)d_in[15];
    const float* bl2 = (const float*)d_in[16];
    float* out = (float*)d_out;

    const int nE = in_sizes[1] / 2;
    const int nN = in_sizes[2];
    const int* src = eidx;
    const int* dst = eidx + nE;
    const int nb = (nN + 127) >> BKT_SHIFT;

    char* ws = (char*)d_ws;
    size_t off = 0;
    auto alloc = [&](size_t bytes) {
        char* p = ws + off;
        off = (off + bytes + 255) & ~(size_t)255;
        return p;
    };
    // bucket_cnt + h adjacent -> one zeroing memset
    int*            bucket_cnt = (int*)alloc((size_t)BKT_MAX * 4);
    float*          h          = (float*)alloc((size_t)3 * N_GRAPHS * 64 * 4);
    int*            row_ptr    = (int*)alloc((size_t)nN * 4);
    int*            deg        = (int*)alloc((size_t)nN * 4);
    unsigned*       ebuf       = (unsigned*)alloc((size_t)nb * CAP * 4);
    int*            csr_src    = (int*)alloc((size_t)nb * CAP * 4);
    unsigned short* xh32       = (unsigned short*)alloc((size_t)nN * 32 * 2);
    unsigned short* yAh        = (unsigned short*)alloc((size_t)nN * 64 * 2);
    unsigned short* yBh        = (unsigned short*)alloc((size_t)nN * 64 * 2);
    unsigned short* aRowsB     = (unsigned short*)alloc((size_t)nN * 64 * 2);

    const int nbChunk = (nE + CHUNK - 1) / CHUNK;

    hipMemsetAsync(bucket_cnt, 0,
                   (char*)(h + 3 * N_GRAPHS * 64) - (char*)bucket_cnt, stream);
    prep_kernel<<<(nN * 32 + 255) / 256, 256, 0, stream>>>(x, xh32, nN);
    bucket_scatter_kernel<<<nbChunk, 256, 0, stream>>>(src, dst, bucket_cnt, ebuf, nE, nb);
    bucket_csr_kernel<<<nb, 256, 0, stream>>>(ebuf, bucket_cnt, row_ptr, deg, csr_src, nN);

    const int nbA = (nN + 3) / 4;
    const int nbT = (nN + 63) / 64;

    aggr_kernel<IN_CH><<<nbA, 256, 0, stream>>>(xh32, t, row_ptr, deg, csr_src, aRowsB, nN);
    transform_kernel<IN_CH, true><<<nbT, 256, 0, stream>>>(
        aRowsB, nullptr, batch, W1r, b1, W1s, yAh, h + 0 * N_GRAPHS * 64, nN);

    aggr_kernel<HID><<<nbA, 256, 0, stream>>>(yAh, t, row_ptr, deg, csr_src, aRowsB, nN);
    transform_kernel<HID, true><<<nbT, 256, 0, stream>>>(
        aRowsB, yAh, batch, W2r, b2, W2s, yBh, h + 1 * N_GRAPHS * 64, nN);

    aggr_kernel<HID><<<nbA, 256, 0, stream>>>(yBh, t, row_ptr, deg, csr_src, aRowsB, nN);
    transform_kernel<HID, false><<<nbT, 256, 0, stream>>>(
        aRowsB, yBh, batch, W3r, b3, W3s, nullptr, h + 2 * N_GRAPHS * 64, nN);

    mlp_kernel<<<N_GRAPHS, 128, 0, stream>>>(h, Wl1, bl1, Wl2, bl2, out);
}